// Round 13
// baseline (36.929 us; speedup 1.0000x reference)
//
#include <hip/hip_runtime.h>
#include <stdint.h>

// out[i] = max((cnts[g_i] + h[g_i]) / (total + N), 0.01),
//   g_i = gdict[i], h[s] = #{ t : gdict[flatten_label[t]] == s }.
//
// Exact data-dependent shortcut (rounds 10-12, validated): the clip floor
// 0.01*T needs ~167K counts in one slot (5000x the 33.5 mean). Per coarse
// bucket B(l)=l>>12, h[gdict[l]] <= bucket_count[B(l)] when the slot has a
// unique contributor; fp add/div monotone => ub <= 0.01 implies out == 0.01
// bit-exactly. Flag-gated exact fallback covers conflicted/undecided slots.
//
// Hard-won gfx950 facts:
//  - global atomics are memory-side write-through at ANY scope (rounds 1/6).
//  - cooperative grid.sync ~100us on 8-XCD MI355X (round 11) -> use kernel
//    boundaries for ordering.
//  - rocclr fillBufferAligned is slow -> zero in-kernel.
//  - LDS atomics issue ~2.1 values/cyc/CU -> 16.7M atomics ~13.6us floor.
//
// Round 13: pair-bucket histogram. Two consecutive tokens -> one cell of a
// nbuck x nbuck pair matrix packed as u16 halves of u32 words (30.7 KB LDS)
// -> 2 LDS atomics per int4 instead of 4 (atomic floor ~6.8us). Carry-safe:
// tokens/block <= 16384 < 65536 (guarded). Per-block reduce: thread b sums
// row b + col b in registers.

#define FBITS     12
#define NBUCK_MAX 256      // shared-kernels bound (pbc thread-write, REPL path)
#define NBUCK_P   160      // pair-path bound (LDS budget)
#define REPL      4
#define GRID_P    1024
#define GRID_A    2048

static inline size_t align256(size_t x) { return (x + 255) & ~(size_t)255; }

// ---- kA_pair: zero flag/conflicted | marker scatter | pair-bucket histogram ----
__global__ __launch_bounds__(256) void kA_pair(const int* __restrict__ labels,
                                               const int* __restrict__ gdict,
                                               uint32_t* __restrict__ pbc,    // [GRID_P][nbuck]
                                               uint32_t* __restrict__ marker, // [nbins] (never pre-zeroed)
                                               uint8_t*  __restrict__ conflicted, // [nbins]
                                               uint32_t* __restrict__ flag,
                                               int n, int llen, int nbins, int nbuck,
                                               int pairWords) {
    extern __shared__ uint32_t h[];    // [pairWords + nbuck]: pair matrix + tail
    int tid = threadIdx.x, bk = blockIdx.x;
    int gtid = bk * 256 + tid;
    int gstride = gridDim.x * 256;

    if (gtid == 0) *flag = 0u;
    for (int i = gtid; i < nbins; i += gstride) conflicted[i] = 0;
    // winner marking: every in-image slot rewritten every call (last-writer-wins)
    for (int l = gtid; l < llen; l += gstride) {
        uint32_t g = (uint32_t)gdict[l];
        if (g < (uint32_t)nbins) marker[g] = (uint32_t)l + 1u;
    }

    int tot = pairWords + nbuck;
    for (int j = tid; j < tot; j += 256) h[j] = 0;
    __syncthreads();

    const int4* l4 = (const int4*)labels;
    int n4 = n >> 2;
    for (int i = gtid; i < n4; i += gstride) {
        int4 q = l4[i];
        uint32_t b0 = ((uint32_t)q.x) >> FBITS, b1 = ((uint32_t)q.y) >> FBITS;
        uint32_t b2 = ((uint32_t)q.z) >> FBITS, b3 = ((uint32_t)q.w) >> FBITS;
        uint32_t p01 = b0 * (uint32_t)nbuck + b1;
        uint32_t p23 = b2 * (uint32_t)nbuck + b3;
        atomicAdd(&h[p01 >> 1], (p01 & 1u) ? 0x10000u : 1u);
        atomicAdd(&h[p23 >> 1], (p23 & 1u) ? 0x10000u : 1u);
    }
    // global tail (n%4 tokens): dedicated per-bucket counters after the matrix
    for (int i = (n4 << 2) + gtid; i < n; i += gstride)
        atomicAdd(&h[pairWords + (((uint32_t)labels[i]) >> FBITS)], 1u);
    __syncthreads();

    // reduce: bucket b's count = row-b sum (first-of-pair) + col-b sum (second) + tail
    if (tid < nbuck) {
        uint32_t rsum = 0, csum = 0;
        int rbase = tid * nbuck;
        for (int j = 0; j < nbuck; ++j) {
            int pr = rbase + j;
            int pc = j * nbuck + tid;
            rsum += (h[pr >> 1] >> ((pr & 1) ? 16 : 0)) & 0xFFFFu;
            csum += (h[pc >> 1] >> ((pc & 1) ? 16 : 0)) & 0xFFFFu;
        }
        pbc[(size_t)bk * nbuck + tid] = rsum + csum + h[pairWords + tid];
    }
}

// ---- tier-2 kA: REPL=4 sub-histograms (round-12 proven) ----
__global__ __launch_bounds__(256) void kA_coarse(const int* __restrict__ labels,
                                                 const int* __restrict__ gdict,
                                                 uint32_t* __restrict__ pbc,    // [GRID_A][nbuck]
                                                 uint32_t* __restrict__ marker,
                                                 uint8_t*  __restrict__ conflicted,
                                                 uint32_t* __restrict__ flag,
                                                 int n, int llen, int nbins, int nbuck) {
    __shared__ uint32_t h[REPL * NBUCK_MAX];
    int tid = threadIdx.x, bk = blockIdx.x;
    int gtid = bk * 256 + tid;
    int gstride = gridDim.x * 256;

    if (gtid == 0) *flag = 0u;
    for (int i = gtid; i < nbins; i += gstride) conflicted[i] = 0;
    for (int l = gtid; l < llen; l += gstride) {
        uint32_t g = (uint32_t)gdict[l];
        if (g < (uint32_t)nbins) marker[g] = (uint32_t)l + 1u;
    }
    for (int j = tid; j < REPL * nbuck; j += 256) h[j] = 0;
    __syncthreads();
    int r = tid & (REPL - 1);
    const int4* l4 = (const int4*)labels;
    int n4 = n >> 2;
    for (int i = gtid; i < n4; i += gstride) {
        int4 q = l4[i];
        atomicAdd(&h[(((uint32_t)q.x) >> FBITS) * REPL + r], 1u);
        atomicAdd(&h[(((uint32_t)q.y) >> FBITS) * REPL + r], 1u);
        atomicAdd(&h[(((uint32_t)q.z) >> FBITS) * REPL + r], 1u);
        atomicAdd(&h[(((uint32_t)q.w) >> FBITS) * REPL + r], 1u);
    }
    for (int i = (n4 << 2) + gtid; i < n; i += gstride)
        atomicAdd(&h[(((uint32_t)labels[i]) >> FBITS) * REPL + r], 1u);
    __syncthreads();
    for (int b = tid; b < nbuck; b += 256)
        pbc[(size_t)bk * nbuck + b] =
            h[b * REPL] + h[b * REPL + 1] + h[b * REPL + 2] + h[b * REPL + 3];
}

// ---- kBC: bucket reduce (blocks < nbuck) | conflict detect (all blocks) ----
__global__ __launch_bounds__(256) void kBC(const uint32_t* __restrict__ pbc,
                                           uint32_t* __restrict__ bc,
                                           const int* __restrict__ gdict,
                                           const uint32_t* __restrict__ marker,
                                           uint8_t* __restrict__ conflicted,
                                           int nblocks, int nbuck, int llen, int nbins) {
    __shared__ uint32_t wsum[4];
    int tid = threadIdx.x, bk = blockIdx.x;
    int gstride = gridDim.x * 256;

    if (bk < nbuck) {
        uint32_t s = 0;
        for (int j = tid; j < nblocks; j += 256) s += pbc[(size_t)j * nbuck + bk];
        for (int o = 32; o > 0; o >>= 1) s += __shfl_down(s, o, 64);
        if ((tid & 63) == 0) wsum[tid >> 6] = s;
        __syncthreads();
        if (tid == 0) bc[bk] = wsum[0] + wsum[1] + wsum[2] + wsum[3];
    }
    for (int l = bk * 256 + tid; l < llen; l += gstride) {
        uint32_t g = (uint32_t)gdict[l];
        if (g < (uint32_t)nbins && marker[g] != (uint32_t)l + 1u)
            conflicted[g] = 1;   // benign same-value race
    }
}

// ---- kD: zero slotsum | decide via upper bound ----
__global__ __launch_bounds__(256) void kD_decide(const int* __restrict__ gdict,
                                                 const float* __restrict__ cnts,
                                                 const uint32_t* __restrict__ bc,
                                                 const uint8_t* __restrict__ conflicted,
                                                 const float* __restrict__ total,
                                                 float* __restrict__ out,
                                                 uint32_t* __restrict__ flag,
                                                 uint32_t* __restrict__ slotsum,
                                                 int llen, int nbins, float nf) {
    int gtid = blockIdx.x * 256 + threadIdx.x;
    int gstride = gridDim.x * 256;

    for (int i = gtid; i < nbins; i += gstride) slotsum[i] = 0u;

    bool undecided = false;
    float T = total[0] + nf;
    for (int i = gtid; i < llen; i += gstride) {
        int gi = gdict[i];
        uint32_t g = (uint32_t)min(max(gi, 0), nbins - 1);   // jax gather clamp
        float v = (cnts[g] + (float)bc[i >> FBITS]) / T;
        bool dec = ((uint32_t)gi < (uint32_t)nbins) && (!conflicted[g]) && (v <= 0.01f);
        if (dec) out[i] = 0.01f;
        else undecided = true;
    }
    if (undecided) atomicOr(flag, 1u);   // rare: trips the exact fallback
}

// ---- guarded exact fallback (no-op when flag==0) ----
__global__ void histG(const uint32_t* __restrict__ flag,
                      const int* __restrict__ labels,
                      const int* __restrict__ gdict,
                      unsigned int* __restrict__ slotsum, int n, int nbins) {
    if (*flag == 0u) return;
    int tid = blockIdx.x * blockDim.x + threadIdx.x;
    int stride = gridDim.x * blockDim.x;
    for (int i = tid; i < n; i += stride) {
        uint32_t g = (uint32_t)gdict[labels[i]];
        if (g < (uint32_t)nbins) atomicAdd(&slotsum[g], 1u);
    }
}

__global__ __launch_bounds__(256) void p5G(const uint32_t* __restrict__ flag,
                                           const int* __restrict__ gdict,
                                           const float* __restrict__ cnts,
                                           const uint32_t* __restrict__ slotsum,
                                           const float* __restrict__ total,
                                           float* __restrict__ out,
                                           int llen, int nbins, float nf) {
    if (*flag == 0u) return;
    int i = blockIdx.x * 256 + threadIdx.x;
    if (i >= llen) return;
    int gi = gdict[i];
    uint32_t g = (uint32_t)min(max(gi, 0), nbins - 1);
    out[i] = fmaxf((cnts[g] + (float)slotsum[g]) / (total[0] + nf), 0.01f);
}

// ---- tier-3: unconditional exact path ----
__global__ void hist_atomic(const int* __restrict__ labels,
                            const int* __restrict__ gdict,
                            unsigned int* __restrict__ ws, int n, int nbins) {
    int tid = blockIdx.x * blockDim.x + threadIdx.x;
    int stride = gridDim.x * blockDim.x;
    for (int i = tid; i < n; i += stride) {
        uint32_t g = (uint32_t)gdict[labels[i]];
        if (g < (uint32_t)nbins) atomicAdd(&ws[g], 1u);
    }
}

__global__ __launch_bounds__(256) void p5_simple(const int* __restrict__ gdict,
                                                 const float* __restrict__ cnts,
                                                 const uint32_t* __restrict__ slotsum,
                                                 const float* __restrict__ total,
                                                 float* __restrict__ out,
                                                 int llen, int nbins, float nf) {
    int i = blockIdx.x * 256 + threadIdx.x;
    if (i < llen) {
        int gi = gdict[i];
        uint32_t g = (uint32_t)min(max(gi, 0), nbins - 1);
        out[i] = fmaxf((cnts[g] + (float)slotsum[g]) / (total[0] + nf), 0.01f);
    }
}

extern "C" void kernel_launch(void* const* d_in, const int* in_sizes, int n_in,
                              void* d_out, int out_size, void* d_ws, size_t ws_size,
                              hipStream_t stream) {
    const int* gdict   = (const int*)d_in[0];
    const int* labels  = (const int*)d_in[1];
    const float* cnts  = (const float*)d_in[3];
    const float* total = (const float*)d_in[4];
    float* out = (float*)d_out;

    int llen  = in_sizes[0];
    int n     = in_sizes[1];
    int nbins = in_sizes[3];
    int nbuck = ((llen - 1) >> FBITS) + 1;
    float nf  = (float)n;

    uint8_t* ws8 = (uint8_t*)d_ws;

    // layout: [flag][bc][conflicted][slotsum][marker][pbc] — all zeroing in-kernel
    size_t o_flag = 0;
    size_t o_bc   = 256;
    size_t o_conf = align256(o_bc + (size_t)nbuck * 4);
    size_t o_slot = align256(o_conf + (size_t)nbins);
    size_t o_mark = align256(o_slot + (size_t)nbins * 4);
    size_t o_pbc  = align256(o_mark + (size_t)nbins * 4);
    size_t needed = o_pbc + (size_t)GRID_A * nbuck * 4;   // sized for the larger grid

    int pairWords = (nbuck * nbuck + 1) / 2;
    size_t ldsPair = (size_t)(pairWords + nbuck) * 4;
    // u16-field carry safety: per-block tokens must stay < 65536
    bool pairSafe = (nbuck <= NBUCK_P) && (ldsPair <= 52 * 1024) &&
                    ((size_t)(n + GRID_P - 1) / GRID_P < 65536);

    if (nbuck <= NBUCK_MAX && needed <= ws_size) {
        uint32_t* flag       = (uint32_t*)(ws8 + o_flag);
        uint32_t* bc         = (uint32_t*)(ws8 + o_bc);
        uint8_t*  conflicted = (uint8_t*)(ws8 + o_conf);
        uint32_t* slotsum    = (uint32_t*)(ws8 + o_slot);
        uint32_t* marker     = (uint32_t*)(ws8 + o_mark);
        uint32_t* pbc        = (uint32_t*)(ws8 + o_pbc);

        int lblocks = (llen + 255) / 256;
        int rows;

        if (pairSafe) {
            rows = GRID_P;
            hipLaunchKernelGGL(kA_pair, dim3(GRID_P), dim3(256), ldsPair, stream,
                               labels, gdict, pbc, marker, conflicted, flag,
                               n, llen, nbins, nbuck, pairWords);
        } else {
            rows = GRID_A;
            hipLaunchKernelGGL(kA_coarse, dim3(GRID_A), dim3(256), 0, stream,
                               labels, gdict, pbc, marker, conflicted, flag,
                               n, llen, nbins, nbuck);
        }
        hipLaunchKernelGGL(kBC, dim3(lblocks), dim3(256), 0, stream,
                           pbc, bc, gdict, marker, conflicted,
                           rows, nbuck, llen, nbins);
        hipLaunchKernelGGL(kD_decide, dim3(lblocks), dim3(256), 0, stream,
                           gdict, cnts, bc, conflicted, total, out, flag, slotsum,
                           llen, nbins, nf);
        hipLaunchKernelGGL(histG, dim3(1024), dim3(256), 0, stream,
                           flag, labels, gdict, (unsigned int*)slotsum, n, nbins);
        hipLaunchKernelGGL(p5G, dim3(lblocks), dim3(256), 0, stream,
                           flag, gdict, cnts, slotsum, total, out, llen, nbins, nf);
    } else {
        uint32_t* ss = (uint32_t*)ws8;
        hipMemsetAsync(ss, 0, (size_t)nbins * 4, stream);
        hipLaunchKernelGGL(hist_atomic, dim3(2048), dim3(256), 0, stream,
                           labels, gdict, (unsigned int*)ss, n, nbins);
        hipLaunchKernelGGL(p5_simple, dim3((llen + 255) / 256), dim3(256), 0, stream,
                           gdict, cnts, ss, total, out, llen, nbins, nf);
    }
}

// Round 14
// 28.902 us; speedup vs baseline: 1.2777x; 1.2777x over previous
//
#include <hip/hip_runtime.h>
#include <stdint.h>

// out[i] = max((cnts[g_i] + h[g_i]) / (total + N), 0.01),
//   g_i = gdict[i], h[s] = #{ t : gdict[flatten_label[t]] == s }.
//
// Exact data-dependent shortcut (rounds 10-12, validated): the clip floor
// 0.01*T needs ~167K counts in one slot (5000x the 33.5 mean). Per coarse
// bucket B(l)=l>>12, h[gdict[l]] <= bucket_count[B(l)] when the slot has a
// unique contributor; fp add/div monotone => ub <= 0.01 implies out == 0.01
// bit-exactly. Flag-gated exact fallback covers conflicted/undecided slots.
//
// Hard-won gfx950 facts:
//  - global atomics are memory-side write-through at ANY scope (rounds 1/6).
//  - cooperative grid.sync ~100us on 8-XCD MI355X (round 11: 3 syncs = 328us).
//  - rocclr fillBufferAligned is slow (tiny fixed grid) -> zero in-kernel.
//  - LDS atomic issue ~2/cyc/CU; pair-packing the values did NOT help
//    (round 13: 36.9us) -> kA is issue/conflict-bound, not value-bound.
//
// Round 14: round-12 structure (proven 28.8us) + REPL 4->8 (984 LDS words,
// halves same-word collisions among the 64 lanes).

#define FBITS     12
#define NBUCK_MAX 256
#define REPL      8
#define GRID_A    2048

static inline size_t align256(size_t x) { return (x + 255) & ~(size_t)255; }

// ---- kA: zero flag/conflicted | marker scatter | coarse label histogram ----
__global__ __launch_bounds__(256) void kA_coarse(const int* __restrict__ labels,
                                                 const int* __restrict__ gdict,
                                                 uint32_t* __restrict__ pbc,    // [GRID_A][nbuck]
                                                 uint32_t* __restrict__ marker, // [nbins] (never pre-zeroed)
                                                 uint8_t*  __restrict__ conflicted, // [nbins]
                                                 uint32_t* __restrict__ flag,
                                                 int n, int llen, int nbins, int nbuck) {
    __shared__ uint32_t h[REPL * NBUCK_MAX];   // 8 KB
    int tid = threadIdx.x, bk = blockIdx.x;
    int gtid = bk * 256 + tid;
    int gstride = gridDim.x * 256;

    if (gtid == 0) *flag = 0u;
    for (int i = gtid; i < nbins; i += gstride) conflicted[i] = 0;
    // winner marking: every in-image slot rewritten every call (last-writer-wins)
    for (int l = gtid; l < llen; l += gstride) {
        uint32_t g = (uint32_t)gdict[l];
        if (g < (uint32_t)nbins) marker[g] = (uint32_t)l + 1u;
    }

    for (int j = tid; j < REPL * nbuck; j += 256) h[j] = 0;
    __syncthreads();

    int r = tid & (REPL - 1);
    const int4* l4 = (const int4*)labels;
    int n4 = n >> 2;
    for (int i = gtid; i < n4; i += gstride) {
        int4 q = l4[i];
        atomicAdd(&h[(((uint32_t)q.x) >> FBITS) * REPL + r], 1u);
        atomicAdd(&h[(((uint32_t)q.y) >> FBITS) * REPL + r], 1u);
        atomicAdd(&h[(((uint32_t)q.z) >> FBITS) * REPL + r], 1u);
        atomicAdd(&h[(((uint32_t)q.w) >> FBITS) * REPL + r], 1u);
    }
    for (int i = (n4 << 2) + gtid; i < n; i += gstride)
        atomicAdd(&h[(((uint32_t)labels[i]) >> FBITS) * REPL + r], 1u);
    __syncthreads();

    for (int b = tid; b < nbuck; b += 256) {
        uint32_t s = 0;
        #pragma unroll
        for (int k = 0; k < REPL; ++k) s += h[b * REPL + k];
        pbc[(size_t)bk * nbuck + b] = s;
    }
}

// ---- kBC: bucket reduce (blocks < nbuck) | conflict detect (all blocks) ----
__global__ __launch_bounds__(256) void kBC(const uint32_t* __restrict__ pbc,
                                           uint32_t* __restrict__ bc,
                                           const int* __restrict__ gdict,
                                           const uint32_t* __restrict__ marker,
                                           uint8_t* __restrict__ conflicted,
                                           int nblocks, int nbuck, int llen, int nbins) {
    __shared__ uint32_t wsum[4];
    int tid = threadIdx.x, bk = blockIdx.x;
    int gstride = gridDim.x * 256;

    if (bk < nbuck) {
        uint32_t s = 0;
        for (int j = tid; j < nblocks; j += 256) s += pbc[(size_t)j * nbuck + bk];
        for (int o = 32; o > 0; o >>= 1) s += __shfl_down(s, o, 64);
        if ((tid & 63) == 0) wsum[tid >> 6] = s;
        __syncthreads();
        if (tid == 0) bc[bk] = wsum[0] + wsum[1] + wsum[2] + wsum[3];
    }
    for (int l = bk * 256 + tid; l < llen; l += gstride) {
        uint32_t g = (uint32_t)gdict[l];
        if (g < (uint32_t)nbins && marker[g] != (uint32_t)l + 1u)
            conflicted[g] = 1;   // benign same-value race
    }
}

// ---- kD: zero slotsum (read only by later histG) | decide via upper bound ----
__global__ __launch_bounds__(256) void kD_decide(const int* __restrict__ gdict,
                                                 const float* __restrict__ cnts,
                                                 const uint32_t* __restrict__ bc,
                                                 const uint8_t* __restrict__ conflicted,
                                                 const float* __restrict__ total,
                                                 float* __restrict__ out,
                                                 uint32_t* __restrict__ flag,
                                                 uint32_t* __restrict__ slotsum,
                                                 int llen, int nbins, float nf) {
    int gtid = blockIdx.x * 256 + threadIdx.x;
    int gstride = gridDim.x * 256;

    for (int i = gtid; i < nbins; i += gstride) slotsum[i] = 0u;

    bool undecided = false;
    float T = total[0] + nf;
    for (int i = gtid; i < llen; i += gstride) {
        int gi = gdict[i];
        uint32_t g = (uint32_t)min(max(gi, 0), nbins - 1);   // jax gather clamp
        float v = (cnts[g] + (float)bc[i >> FBITS]) / T;
        bool dec = ((uint32_t)gi < (uint32_t)nbins) && (!conflicted[g]) && (v <= 0.01f);
        if (dec) out[i] = 0.01f;
        else undecided = true;
    }
    if (undecided) atomicOr(flag, 1u);   // rare: trips the exact fallback
}

// ---- guarded exact fallback (no-op when flag==0) ----
__global__ void histG(const uint32_t* __restrict__ flag,
                      const int* __restrict__ labels,
                      const int* __restrict__ gdict,
                      unsigned int* __restrict__ slotsum, int n, int nbins) {
    if (*flag == 0u) return;
    int tid = blockIdx.x * blockDim.x + threadIdx.x;
    int stride = gridDim.x * blockDim.x;
    for (int i = tid; i < n; i += stride) {
        uint32_t g = (uint32_t)gdict[labels[i]];
        if (g < (uint32_t)nbins) atomicAdd(&slotsum[g], 1u);
    }
}

__global__ __launch_bounds__(256) void p5G(const uint32_t* __restrict__ flag,
                                           const int* __restrict__ gdict,
                                           const float* __restrict__ cnts,
                                           const uint32_t* __restrict__ slotsum,
                                           const float* __restrict__ total,
                                           float* __restrict__ out,
                                           int llen, int nbins, float nf) {
    if (*flag == 0u) return;
    int i = blockIdx.x * 256 + threadIdx.x;
    if (i >= llen) return;
    int gi = gdict[i];
    uint32_t g = (uint32_t)min(max(gi, 0), nbins - 1);
    out[i] = fmaxf((cnts[g] + (float)slotsum[g]) / (total[0] + nf), 0.01f);
}

// ---- tier-3: unconditional exact path ----
__global__ void hist_atomic(const int* __restrict__ labels,
                            const int* __restrict__ gdict,
                            unsigned int* __restrict__ ws, int n, int nbins) {
    int tid = blockIdx.x * blockDim.x + threadIdx.x;
    int stride = gridDim.x * blockDim.x;
    for (int i = tid; i < n; i += stride) {
        uint32_t g = (uint32_t)gdict[labels[i]];
        if (g < (uint32_t)nbins) atomicAdd(&ws[g], 1u);
    }
}

__global__ __launch_bounds__(256) void p5_simple(const int* __restrict__ gdict,
                                                 const float* __restrict__ cnts,
                                                 const uint32_t* __restrict__ slotsum,
                                                 const float* __restrict__ total,
                                                 float* __restrict__ out,
                                                 int llen, int nbins, float nf) {
    int i = blockIdx.x * 256 + threadIdx.x;
    if (i < llen) {
        int gi = gdict[i];
        uint32_t g = (uint32_t)min(max(gi, 0), nbins - 1);
        out[i] = fmaxf((cnts[g] + (float)slotsum[g]) / (total[0] + nf), 0.01f);
    }
}

extern "C" void kernel_launch(void* const* d_in, const int* in_sizes, int n_in,
                              void* d_out, int out_size, void* d_ws, size_t ws_size,
                              hipStream_t stream) {
    const int* gdict   = (const int*)d_in[0];
    const int* labels  = (const int*)d_in[1];
    const float* cnts  = (const float*)d_in[3];
    const float* total = (const float*)d_in[4];
    float* out = (float*)d_out;

    int llen  = in_sizes[0];
    int n     = in_sizes[1];
    int nbins = in_sizes[3];
    int nbuck = ((llen - 1) >> FBITS) + 1;
    float nf  = (float)n;

    uint8_t* ws8 = (uint8_t*)d_ws;

    // layout: [flag][bc][conflicted][slotsum][marker][pbc] — all zeroing in-kernel
    size_t o_flag = 0;
    size_t o_bc   = 256;
    size_t o_conf = align256(o_bc + (size_t)nbuck * 4);
    size_t o_slot = align256(o_conf + (size_t)nbins);
    size_t o_mark = align256(o_slot + (size_t)nbins * 4);
    size_t o_pbc  = align256(o_mark + (size_t)nbins * 4);
    size_t needed = o_pbc + (size_t)GRID_A * nbuck * 4;

    if (nbuck <= NBUCK_MAX && needed <= ws_size) {
        uint32_t* flag       = (uint32_t*)(ws8 + o_flag);
        uint32_t* bc         = (uint32_t*)(ws8 + o_bc);
        uint8_t*  conflicted = (uint8_t*)(ws8 + o_conf);
        uint32_t* slotsum    = (uint32_t*)(ws8 + o_slot);
        uint32_t* marker     = (uint32_t*)(ws8 + o_mark);
        uint32_t* pbc        = (uint32_t*)(ws8 + o_pbc);

        int lblocks = (llen + 255) / 256;

        hipLaunchKernelGGL(kA_coarse, dim3(GRID_A), dim3(256), 0, stream,
                           labels, gdict, pbc, marker, conflicted, flag,
                           n, llen, nbins, nbuck);
        hipLaunchKernelGGL(kBC, dim3(lblocks), dim3(256), 0, stream,
                           pbc, bc, gdict, marker, conflicted,
                           GRID_A, nbuck, llen, nbins);
        hipLaunchKernelGGL(kD_decide, dim3(lblocks), dim3(256), 0, stream,
                           gdict, cnts, bc, conflicted, total, out, flag, slotsum,
                           llen, nbins, nf);
        hipLaunchKernelGGL(histG, dim3(1024), dim3(256), 0, stream,
                           flag, labels, gdict, (unsigned int*)slotsum, n, nbins);
        hipLaunchKernelGGL(p5G, dim3(lblocks), dim3(256), 0, stream,
                           flag, gdict, cnts, slotsum, total, out, llen, nbins, nf);
    } else {
        uint32_t* ss = (uint32_t*)ws8;
        hipMemsetAsync(ss, 0, (size_t)nbins * 4, stream);
        hipLaunchKernelGGL(hist_atomic, dim3(2048), dim3(256), 0, stream,
                           labels, gdict, (unsigned int*)ss, n, nbins);
        hipLaunchKernelGGL(p5_simple, dim3((llen + 255) / 256), dim3(256), 0, stream,
                           gdict, cnts, ss, total, out, llen, nbins, nf);
    }
}